// Round 7
// baseline (761.281 us; speedup 1.0000x reference)
//
#include <hip/hip_runtime.h>

#define H 128
#define TDEPTH 10
#define NPT 1023
#define NTREES 512
#define PAD 136       // LDS row stride in bf16 (272 B, 16B-aligned, 2-way banks)
#define XSB 160       // x-staging base row

typedef unsigned short bf16_t;
typedef __attribute__((ext_vector_type(8))) short bf16x8;
typedef __attribute__((ext_vector_type(4))) float f32x4;

__device__ __forceinline__ float sig_(float x) { return 1.0f / (1.0f + __expf(-x)); }
__device__ __forceinline__ float th_(float x)  { return 1.0f - 2.0f / (__expf(2.0f * x) + 1.0f); }
__device__ __forceinline__ float b2f(bf16_t u) {
    union { float f; unsigned int u; } v; v.u = ((unsigned int)u) << 16; return v.f;
}
__device__ __forceinline__ bf16_t f2b(float f) {
    union { float f; unsigned int u; } v; v.f = f;
    return (bf16_t)((v.u + 0x7fffu + ((v.u >> 16) & 1u)) >> 16);   // RNE
}
__device__ __forceinline__ bf16x8 ld8(const bf16_t* p) {
    return *reinterpret_cast<const bf16x8*>(p);
}
#define MFMA(a,b,c) __builtin_amdgcn_mfma_f32_16x16x32_bf16(a,b,c,0,0,0)

// ---------------------------------------------------------------------------
// Weight pack, plane-interleaved: Wb[(feat*8 + p)*128 + k]
// p: 0 Wi | 1 Wo | 2 Wu | 3 Ui | 4 Uo | 5 Uu | 6 Wf | 7 Uf
// ---------------------------------------------------------------------------
__global__ void pack_weights(const float* __restrict__ W_iou, const float* __restrict__ U_iou,
                             const float* __restrict__ W_f,   const float* __restrict__ U_f,
                             bf16_t* __restrict__ Wb)
{
    int i = blockIdx.x * 256 + threadIdx.x;   // 0 .. 131071
    int k    = i & 127;
    int p    = (i >> 7) & 7;
    int feat = i >> 10;
    float v;
    switch (p) {
        case 0: v = W_iou[(      feat) * H + k]; break;
        case 1: v = W_iou[(128 + feat) * H + k]; break;
        case 2: v = W_iou[(256 + feat) * H + k]; break;
        case 3: v = U_iou[(      feat) * H + k]; break;
        case 4: v = U_iou[(128 + feat) * H + k]; break;
        case 5: v = U_iou[(256 + feat) * H + k]; break;
        case 6: v = W_f  [feat * H + k]; break;
        default: v = U_f [feat * H + k]; break;
    }
    Wb[i] = f2b(v);
}

__global__ void pack_E(const float* __restrict__ E, bf16_t* __restrict__ Eb)
{
    int i = blockIdx.x * 256 + threadIdx.x;
    Eb[i] = f2b(E[i]);
}

// ---------------------------------------------------------------------------
// One level-phase inside a fused kernel.
// LDS row map (192 rows of PAD bf16):
//   CH (first phase children): H0 0-31 | H1 32-63 | C0 64-95 | C1 96-127 | HS 128-159
//   OUT(p) at base 80*p: H0 +0(16) | H1 +16 | C0 +32 | C1 +48 | HS +64
//   XS rows 160-191
// Phase parity p = PH&1; children read from CH (PH==0) or OUT(p^1).
// ---------------------------------------------------------------------------
template<int NODES, int LEAF, int PH>
__device__ __forceinline__ void phase_body(
    bf16_t* lds, const int* wordid, const bf16_t* Eb, const bf16_t* wbase,
    float bi, float bo, float bu, float bfv,
    const float* W_out, const float* b_out, float* out,
    bf16_t* h_out, bf16_t* c_out, bf16_t* hs_out, int write_out,
    int l, int tid, int l15, int kg, int feat)
{
    const int n0 = (int)blockIdx.x * NODES;
    constexpr int p   = PH & 1;
    constexpr int rH0 = (PH == 0) ? 0   : 80 * (p ^ 1) + 0;
    constexpr int rH1 = (PH == 0) ? 32  : 80 * (p ^ 1) + 16;
    constexpr int rC0 = (PH == 0) ? 64  : 80 * (p ^ 1) + 32;
    constexpr int rC1 = (PH == 0) ? 96  : 80 * (p ^ 1) + 48;
    constexpr int rHS = (PH == 0) ? 128 : 80 * (p ^ 1) + 64;
    constexpr int ob  = 80 * p;

    // stage x for this phase's nodes
    for (int idx = tid; idx < NODES * 16; idx += 512) {
        int q = idx & 15, m = idx >> 4;
        int g = n0 + m;
        int t = g >> l, i = g & ((1 << l) - 1);
        int wid = wordid[t * NPT + (1 << l) - 1 + i];
        *(uint4*)&lds[(XSB + m) * PAD + q * 8] = *(const uint4*)(Eb + (size_t)wid * H + q * 8);
    }
    __syncthreads();

    constexpr int MT = (NODES > 16) ? 2 : 1;
    f32x4 z = {0.f, 0.f, 0.f, 0.f};
    f32x4 ai[MT], ao[MT], au[MT], afx[MT], af0[MT], af1[MT];
#pragma unroll
    for (int m = 0; m < MT; ++m) { ai[m]=z; ao[m]=z; au[m]=z; afx[m]=z; af0[m]=z; af1[m]=z; }

#pragma unroll
    for (int ks = 0; ks < 4; ++ks) {
        const int kc = ks * 32 + kg * 8;
        if (LEAF) {
            bf16x8 W0 = ld8(wbase + ks * 32 + 0 * 128);
            bf16x8 W1 = ld8(wbase + ks * 32 + 1 * 128);
            bf16x8 W2 = ld8(wbase + ks * 32 + 2 * 128);
#pragma unroll
            for (int mt = 0; mt < MT; ++mt) {
                bf16x8 xa = ld8(&lds[(XSB + mt * 16 + l15) * PAD + kc]);
                ai[mt] = MFMA(xa, W0, ai[mt]);
                ao[mt] = MFMA(xa, W1, ao[mt]);
                au[mt] = MFMA(xa, W2, au[mt]);
            }
        } else {
            bf16x8 W0 = ld8(wbase + ks * 32 + 0 * 128);
            bf16x8 W1 = ld8(wbase + ks * 32 + 1 * 128);
            bf16x8 W2 = ld8(wbase + ks * 32 + 2 * 128);
            bf16x8 W3 = ld8(wbase + ks * 32 + 3 * 128);
            bf16x8 W4 = ld8(wbase + ks * 32 + 4 * 128);
            bf16x8 W5 = ld8(wbase + ks * 32 + 5 * 128);
            bf16x8 W6 = ld8(wbase + ks * 32 + 6 * 128);
            bf16x8 W7 = ld8(wbase + ks * 32 + 7 * 128);
#pragma unroll
            for (int mt = 0; mt < MT; ++mt) {
                const int row = mt * 16 + l15;
                bf16x8 xa  = ld8(&lds[(XSB + row) * PAD + kc]);
                bf16x8 hsa = ld8(&lds[(rHS + row) * PAD + kc]);
                bf16x8 h0a = ld8(&lds[(rH0 + row) * PAD + kc]);
                bf16x8 h1a = ld8(&lds[(rH1 + row) * PAD + kc]);
                ai[mt]  = MFMA(hsa, W3, MFMA(xa, W0, ai[mt]));
                ao[mt]  = MFMA(hsa, W4, MFMA(xa, W1, ao[mt]));
                au[mt]  = MFMA(hsa, W5, MFMA(xa, W2, au[mt]));
                afx[mt] = MFMA(xa,  W6, afx[mt]);
                af0[mt] = MFMA(h0a, W7, af0[mt]);
                af1[mt] = MFMA(h1a, W7, af1[mt]);
            }
        }
    }

    // epilogue compute (regs only; reads child-c LDS)
    float hv[MT * 4], cv[MT * 4];
#pragma unroll
    for (int mt = 0; mt < MT; ++mt) {
#pragma unroll
        for (int r = 0; r < 4; ++r) {
            int nb = mt * 16 + kg * 4 + r;
            float iv = sig_(ai[mt][r] + bi);
            float ov = sig_(ao[mt][r] + bo);
            float uv = th_ (au[mt][r] + bu);
            float cl;
            if (LEAF) {
                cl = iv * uv;
            } else {
                float fx = afx[mt][r];
                float f0 = sig_(fx + af0[mt][r] + bfv);
                float f1 = sig_(fx + af1[mt][r] + bfv);
                float c0 = b2f(lds[(rC0 + nb) * PAD + feat]);
                float c1 = b2f(lds[(rC1 + nb) * PAD + feat]);
                cl = iv * uv + f0 * c0 + f1 * c1;
            }
            hv[mt * 4 + r] = ov * th_(cl);
            cv[mt * 4 + r] = cl;
        }
    }
    __syncthreads();   // all reads of child buffers done before overwriting overlays

    // write OUT(p) LDS (+ HBM if last phase of kernel)
#pragma unroll
    for (int mt = 0; mt < MT; ++mt) {
        float hp = 0.f;
#pragma unroll
        for (int r = 0; r < 4; ++r) {
            int nb = mt * 16 + kg * 4 + r;
            float hl = hv[mt * 4 + r], cl = cv[mt * 4 + r];
            if (nb < NODES) {
                lds[(ob + (nb & 1) * 16 + (nb >> 1)) * PAD + feat]      = f2b(hl);
                lds[(ob + 32 + (nb & 1) * 16 + (nb >> 1)) * PAD + feat] = f2b(cl);
                if (write_out) {
                    h_out[(size_t)(n0 + nb) * H + feat] = f2b(hl);
                    c_out[(size_t)(n0 + nb) * H + feat] = f2b(cl);
                }
                if (r & 1) {
                    float hs = hp + hl;
                    lds[(ob + 64 + (nb >> 1)) * PAD + feat] = f2b(hs);
                    if (write_out) hs_out[(size_t)((n0 + nb) >> 1) * H + feat] = f2b(hs);
                } else {
                    hp = hl;
                }
            }
        }
    }
    __syncthreads();

    // logits for this level from LDS h
    if (tid < NODES * 5) {
        int i = tid / 5, c = tid - i * 5;
        const bf16_t* hrow = &lds[(ob + (i & 1) * 16 + (i >> 1)) * PAD];
        const float* wo = W_out + c * H;
        float s = 0.f;
#pragma unroll 4
        for (int f = 0; f < H; f += 8) {
            uint4 raw = *(const uint4*)&hrow[f];
            s += b2f(raw.x & 0xffff) * wo[f]     + b2f(raw.x >> 16) * wo[f + 1]
               + b2f(raw.y & 0xffff) * wo[f + 2] + b2f(raw.y >> 16) * wo[f + 3]
               + b2f(raw.z & 0xffff) * wo[f + 4] + b2f(raw.z >> 16) * wo[f + 5]
               + b2f(raw.w & 0xffff) * wo[f + 6] + b2f(raw.w >> 16) * wo[f + 7];
        }
        int g = n0 + i, t = g >> l, il = g & ((1 << l) - 1);
        out[(size_t)(t * NPT + (1 << l) - 1 + il) * 5 + c] = s + b_out[c];
    }
    // no trailing barrier: next phase stages XS (disjoint region) then barriers
}

// ---------------------------------------------------------------------------
// Fused multi-level kernel: block owns a subtree slice (32 top-level nodes).
// ---------------------------------------------------------------------------
template<int LEAF0, int NPH>
__global__ __launch_bounds__(512) void tree_fused(
    const int* __restrict__ wordid, const bf16_t* __restrict__ Eb,
    const bf16_t* __restrict__ Wb,
    const float* __restrict__ b_iou, const float* __restrict__ b_Uiou,
    const float* __restrict__ b_Wf,  const float* __restrict__ b_Uf,
    const bf16_t* __restrict__ h_in, const bf16_t* __restrict__ c_in,
    const bf16_t* __restrict__ hs_in,
    bf16_t* __restrict__ h_out, bf16_t* __restrict__ c_out, bf16_t* __restrict__ hs_out,
    const float* __restrict__ W_out, const float* __restrict__ b_out,
    float* __restrict__ out,
    int lhi, int write_last)
{
    __shared__ __align__(16) bf16_t lds[192 * PAD];

    const int tid  = threadIdx.x;
    const int lane = tid & 63;
    const int w    = tid >> 6;
    const int l15  = lane & 15;
    const int kg   = lane >> 4;
    const int feat = w * 16 + l15;
    const bf16_t* wbase = Wb + (size_t)feat * 1024 + kg * 8;

    const float bi  = b_iou[      feat] + b_Uiou[      feat];
    const float bo  = b_iou[128 + feat] + b_Uiou[128 + feat];
    const float bu  = b_iou[256 + feat] + b_Uiou[256 + feat];
    const float bfv = b_Wf[feat] + b_Uf[feat];

    if (!LEAF0) {
        // stage first-phase children from HBM: h (64 rows, split), c (64), hs (32)
        int n0 = (int)blockIdx.x * 32;
        for (int idx = tid; idx < 2560; idx += 512) {
            int q = idx & 15, rr = idx >> 4;
            const bf16_t* src; int dst;
            if (rr < 64)       { int j = rr;       src = h_in  + (size_t)(2 * n0 + j) * H; dst = (j & 1) * 32 + (j >> 1); }
            else if (rr < 128) { int j = rr - 64;  src = c_in  + (size_t)(2 * n0 + j) * H; dst = 64 + (j & 1) * 32 + (j >> 1); }
            else               { int j = rr - 128; src = hs_in + (size_t)(n0 + j) * H;     dst = 128 + j; }
            *(uint4*)&lds[dst * PAD + q * 8] = *(const uint4*)(src + q * 8);
        }
        // phase_body's post-staging barrier covers this
    }

    phase_body<32, LEAF0, 0>(lds, wordid, Eb, wbase, bi, bo, bu, bfv,
                             W_out, b_out, out, h_out, c_out, hs_out,
                             (NPH == 1) ? write_last : 0, lhi, tid, l15, kg, feat);
    if (NPH >= 2)
        phase_body<16, 0, 1>(lds, wordid, Eb, wbase, bi, bo, bu, bfv,
                             W_out, b_out, out, h_out, c_out, hs_out,
                             (NPH == 2) ? write_last : 0, lhi - 1, tid, l15, kg, feat);
    if (NPH >= 3)
        phase_body<8, 0, 2>(lds, wordid, Eb, wbase, bi, bo, bu, bfv,
                            W_out, b_out, out, h_out, c_out, hs_out,
                            (NPH == 3) ? write_last : 0, lhi - 2, tid, l15, kg, feat);
    if (NPH >= 4)
        phase_body<4, 0, 3>(lds, wordid, Eb, wbase, bi, bo, bu, bfv,
                            W_out, b_out, out, h_out, c_out, hs_out,
                            (NPH == 4) ? write_last : 0, lhi - 3, tid, l15, kg, feat);
}

// ---------------------------------------------------------------------------
extern "C" void kernel_launch(void* const* d_in, const int* in_sizes, int n_in,
                              void* d_out, int out_size, void* d_ws, size_t ws_size,
                              hipStream_t stream)
{
    (void)in_sizes; (void)n_in; (void)out_size; (void)ws_size;
    const int*   wordid = (const int*)  d_in[0];
    const float* E      = (const float*)d_in[1];
    const float* W_iou  = (const float*)d_in[2];
    const float* b_iou  = (const float*)d_in[3];
    const float* U_iou  = (const float*)d_in[4];
    const float* b_Uiou = (const float*)d_in[5];
    const float* W_f    = (const float*)d_in[6];
    const float* b_Wf   = (const float*)d_in[7];
    const float* U_f    = (const float*)d_in[8];
    const float* b_Uf   = (const float*)d_in[9];
    const float* W_out  = (const float*)d_in[10];
    const float* b_out  = (const float*)d_in[11];
    float* out = (float*)d_out;

    // ws layout (bf16 elements): Wb | Eb | h8 c8 hs8 | h6 c6 hs6 | h4 c4 hs4
    bf16_t* Wb  = (bf16_t*)d_ws;
    bf16_t* Eb  = Wb  + (size_t)1024 * H;
    bf16_t* h8  = Eb  + (size_t)32000 * H;
    bf16_t* c8  = h8  + (size_t)131072 * H;
    bf16_t* hs8 = c8  + (size_t)131072 * H;
    bf16_t* h6  = hs8 + (size_t)65536 * H;
    bf16_t* c6  = h6  + (size_t)32768 * H;
    bf16_t* hs6 = c6  + (size_t)32768 * H;
    bf16_t* h4  = hs6 + (size_t)16384 * H;
    bf16_t* c4  = h4  + (size_t)8192 * H;
    bf16_t* hs4 = c4  + (size_t)8192 * H;

    pack_weights<<<512, 256, 0, stream>>>(W_iou, U_iou, W_f, U_f, Wb);
    pack_E<<<16000, 256, 0, stream>>>(E, Eb);

    // levels 9+8
    tree_fused<1, 2><<<8192, 512, 0, stream>>>(
        wordid, Eb, Wb, b_iou, b_Uiou, b_Wf, b_Uf,
        (const bf16_t*)0, (const bf16_t*)0, (const bf16_t*)0,
        h8, c8, hs8, W_out, b_out, out, 9, 1);
    // levels 7+6
    tree_fused<0, 2><<<2048, 512, 0, stream>>>(
        wordid, Eb, Wb, b_iou, b_Uiou, b_Wf, b_Uf,
        h8, c8, hs8, h6, c6, hs6, W_out, b_out, out, 7, 1);
    // levels 5+4
    tree_fused<0, 2><<<512, 512, 0, stream>>>(
        wordid, Eb, Wb, b_iou, b_Uiou, b_Wf, b_Uf,
        h6, c6, hs6, h4, c4, hs4, W_out, b_out, out, 5, 1);
    // levels 3..0
    tree_fused<0, 4><<<128, 512, 0, stream>>>(
        wordid, Eb, Wb, b_iou, b_Uiou, b_Wf, b_Uf,
        h4, c4, hs4, (bf16_t*)0, (bf16_t*)0, (bf16_t*)0,
        W_out, b_out, out, 3, 0);
}

// Round 8
// 646.161 us; speedup vs baseline: 1.1782x; 1.1782x over previous
//
#include <hip/hip_runtime.h>

#define H 128
#define TDEPTH 10
#define NPT 1023
#define NTREES 512
#define PAD 136       // LDS row stride in bf16 (272 B, 16B-aligned)

typedef unsigned short bf16_t;
typedef __attribute__((ext_vector_type(8))) short bf16x8;
typedef __attribute__((ext_vector_type(4))) float f32x4;

__device__ __forceinline__ float sig_(float x) { return 1.0f / (1.0f + __expf(-x)); }
__device__ __forceinline__ float th_(float x)  { return 1.0f - 2.0f / (__expf(2.0f * x) + 1.0f); }
__device__ __forceinline__ float b2f(bf16_t u) {
    union { float f; unsigned int u; } v; v.u = ((unsigned int)u) << 16; return v.f;
}
__device__ __forceinline__ bf16_t f2b(float f) {
    union { float f; unsigned int u; } v; v.f = f;
    return (bf16_t)((v.u + 0x7fffu + ((v.u >> 16) & 1u)) >> 16);   // RNE
}
__device__ __forceinline__ bf16x8 ld8(const bf16_t* p) {
    return *reinterpret_cast<const bf16x8*>(p);
}
#define MFMA(a,b,c) __builtin_amdgcn_mfma_f32_16x16x32_bf16(a,b,c,0,0,0)

// ---------------------------------------------------------------------------
// Weight pack, plane-interleaved: Wb[(feat*8 + p)*128 + k]
// p: 0 Wi | 1 Wo | 2 Wu | 3 Ui | 4 Uo | 5 Uu | 6 Wf | 7 Uf
// ---------------------------------------------------------------------------
__global__ void pack_weights(const float* __restrict__ W_iou, const float* __restrict__ U_iou,
                             const float* __restrict__ W_f,   const float* __restrict__ U_f,
                             bf16_t* __restrict__ Wb)
{
    int i = blockIdx.x * 256 + threadIdx.x;   // 0 .. 131071
    int k    = i & 127;
    int p    = (i >> 7) & 7;
    int feat = i >> 10;
    float v;
    switch (p) {
        case 0: v = W_iou[(      feat) * H + k]; break;
        case 1: v = W_iou[(128 + feat) * H + k]; break;
        case 2: v = W_iou[(256 + feat) * H + k]; break;
        case 3: v = U_iou[(      feat) * H + k]; break;
        case 4: v = U_iou[(128 + feat) * H + k]; break;
        case 5: v = U_iou[(256 + feat) * H + k]; break;
        case 6: v = W_f  [feat * H + k]; break;
        default: v = U_f [feat * H + k]; break;
    }
    Wb[i] = f2b(v);
}

__global__ void pack_E(const float* __restrict__ E, bf16_t* __restrict__ Eb)
{
    int i = blockIdx.x * 256 + threadIdx.x;
    Eb[i] = f2b(E[i]);
}

// ---------------------------------------------------------------------------
// Leaf (l=9): 64 nodes/block, 512 threads = 8 feat-waves (16 feats each).
// ---------------------------------------------------------------------------
__global__ __launch_bounds__(512, 4) void leaf_mfma(
    const int* __restrict__ wordid, const bf16_t* __restrict__ Eb,
    const bf16_t* __restrict__ Wb,
    const float* __restrict__ b_iou, const float* __restrict__ b_Uiou,
    bf16_t* __restrict__ h_cur, bf16_t* __restrict__ c_cur,
    bf16_t* __restrict__ hs_cur, int t0)
{
    const int level = TDEPTH - 1;
    __shared__ __align__(16) bf16_t x_s[64][PAD];

    const int tid = threadIdx.x;
    const int n0  = blockIdx.x * 64;

    for (int idx = tid; idx < 1024; idx += 512) {
        int q = idx & 15;
        int m = idx >> 4;
        int g = n0 + m;
        int t = g >> level, i = g & ((1 << level) - 1);
        int wid = wordid[(t0 + t) * NPT + (1 << level) - 1 + i];
        *(uint4*)&x_s[m][q * 8] = *(const uint4*)(Eb + (size_t)wid * H + q * 8);
    }
    __syncthreads();

    const int lane = tid & 63;
    const int w    = tid >> 6;
    const int l15  = lane & 15;
    const int kg   = lane >> 4;
    const int feat = w * 16 + l15;
    const bf16_t* wbase = Wb + (size_t)feat * 1024 + kg * 8;

    f32x4 z = {0.f, 0.f, 0.f, 0.f};
    f32x4 acc[3][4];
#pragma unroll
    for (int g = 0; g < 3; ++g)
#pragma unroll
        for (int m = 0; m < 4; ++m) acc[g][m] = z;

#pragma unroll
    for (int ks = 0; ks < 4; ++ks) {
        bf16x8 W0 = ld8(wbase + ks * 32 + 0 * 128);
        bf16x8 W1 = ld8(wbase + ks * 32 + 1 * 128);
        bf16x8 W2 = ld8(wbase + ks * 32 + 2 * 128);
        const int kc = ks * 32 + kg * 8;
#pragma unroll
        for (int mt = 0; mt < 4; ++mt) {
            bf16x8 xa = ld8(&x_s[mt * 16 + l15][kc]);
            acc[0][mt] = MFMA(xa, W0, acc[0][mt]);
            acc[1][mt] = MFMA(xa, W1, acc[1][mt]);
            acc[2][mt] = MFMA(xa, W2, acc[2][mt]);
        }
    }

    float bi = b_iou[      feat] + b_Uiou[      feat];
    float bo = b_iou[128 + feat] + b_Uiou[128 + feat];
    float bu = b_iou[256 + feat] + b_Uiou[256 + feat];
#pragma unroll
    for (int mt = 0; mt < 4; ++mt) {
        float hpair = 0.f;
#pragma unroll
        for (int r = 0; r < 4; ++r) {
            int g = n0 + mt * 16 + kg * 4 + r;
            float iv = sig_(acc[0][mt][r] + bi);
            float ov = sig_(acc[1][mt][r] + bo);
            float uv = th_ (acc[2][mt][r] + bu);
            float cl = iv * uv;
            float hl = ov * th_(cl);
            h_cur[(size_t)g * H + feat] = f2b(hl);
            c_cur[(size_t)g * H + feat] = f2b(cl);
            if (r & 1) hs_cur[(size_t)(g >> 1) * H + feat] = f2b(hpair + hl);
            else       hpair = hl;
        }
    }
}

// ---------------------------------------------------------------------------
// Internal level l: 32 nodes/block, 512 threads. LDS: x, h0, h1, hs (35 KB).
// c_prev prefetched to registers. Single barrier. Tail computes logits for the
// CHILDREN (level l+1) from the already-staged h0_s/h1_s.
// ---------------------------------------------------------------------------
__global__ __launch_bounds__(512, 4) void internal_mfma(
    const int* __restrict__ wordid, const bf16_t* __restrict__ Eb,
    const bf16_t* __restrict__ Wb,
    const float* __restrict__ b_iou, const float* __restrict__ b_Uiou,
    const float* __restrict__ b_Wf,  const float* __restrict__ b_Uf,
    const bf16_t* __restrict__ h_prev, const bf16_t* __restrict__ c_prev,
    const bf16_t* __restrict__ hs_prev,
    bf16_t* __restrict__ h_cur, bf16_t* __restrict__ c_cur,
    bf16_t* __restrict__ hs_cur,
    const float* __restrict__ W_out, const float* __restrict__ b_out,
    float* __restrict__ out,
    int level, int t0, int write_hs)
{
    __shared__ __align__(16) bf16_t x_s [32][PAD];
    __shared__ __align__(16) bf16_t h0_s[32][PAD];
    __shared__ __align__(16) bf16_t h1_s[32][PAD];
    __shared__ __align__(16) bf16_t hs_s[32][PAD];

    const int tid = threadIdx.x;
    const int n0  = blockIdx.x * 32;

    const int lane = tid & 63;
    const int w    = tid >> 6;
    const int l15  = lane & 15;
    const int kg   = lane >> 4;
    const int feat = w * 16 + l15;

    // stage: x (32 rows), children h (64 rows split even/odd), hs (32 rows)
    for (int idx = tid; idx < 2048; idx += 512) {
        int q = idx & 15, rr = idx >> 4;
        const bf16_t* src; bf16_t* dst;
        if (rr < 32) {
            int g = n0 + rr;
            int t = g >> level, i = g & ((1 << level) - 1);
            int wid = wordid[(t0 + t) * NPT + (1 << level) - 1 + i];
            src = Eb + (size_t)wid * H; dst = &x_s[rr][0];
        } else if (rr < 96) {
            int j = rr - 32;
            src = h_prev + (size_t)(2 * n0 + j) * H;
            dst = (j & 1) ? &h1_s[j >> 1][0] : &h0_s[j >> 1][0];
        } else {
            int j = rr - 96;
            src = hs_prev + (size_t)(n0 + j) * H; dst = &hs_s[j][0];
        }
        *(uint4*)(dst + q * 8) = *(const uint4*)(src + q * 8);
    }

    // prefetch child c values for this thread's epilogue (latency hidden by MFMA)
    float c0p[2][4], c1p[2][4];
#pragma unroll
    for (int mt = 0; mt < 2; ++mt)
#pragma unroll
        for (int r = 0; r < 4; ++r) {
            int node = n0 + mt * 16 + kg * 4 + r;
            c0p[mt][r] = b2f(c_prev[(size_t)(2 * node)     * H + feat]);
            c1p[mt][r] = b2f(c_prev[(size_t)(2 * node + 1) * H + feat]);
        }

    __syncthreads();

    const bf16_t* wbase = Wb + (size_t)feat * 1024 + kg * 8;
    f32x4 z = {0.f, 0.f, 0.f, 0.f};
    f32x4 acc[6][2];
#pragma unroll
    for (int g = 0; g < 6; ++g)
#pragma unroll
        for (int m = 0; m < 2; ++m) acc[g][m] = z;

#pragma unroll
    for (int ks = 0; ks < 4; ++ks) {
        bf16x8 W0 = ld8(wbase + ks * 32 + 0 * 128);
        bf16x8 W1 = ld8(wbase + ks * 32 + 1 * 128);
        bf16x8 W2 = ld8(wbase + ks * 32 + 2 * 128);
        bf16x8 W3 = ld8(wbase + ks * 32 + 3 * 128);
        bf16x8 W4 = ld8(wbase + ks * 32 + 4 * 128);
        bf16x8 W5 = ld8(wbase + ks * 32 + 5 * 128);
        bf16x8 W6 = ld8(wbase + ks * 32 + 6 * 128);
        bf16x8 W7 = ld8(wbase + ks * 32 + 7 * 128);
        const int kc = ks * 32 + kg * 8;
#pragma unroll
        for (int mt = 0; mt < 2; ++mt) {
            const int row = mt * 16 + l15;
            bf16x8 xa  = ld8(&x_s [row][kc]);
            bf16x8 hsa = ld8(&hs_s[row][kc]);
            bf16x8 h0a = ld8(&h0_s[row][kc]);
            bf16x8 h1a = ld8(&h1_s[row][kc]);
            acc[0][mt] = MFMA(hsa, W3, MFMA(xa, W0, acc[0][mt]));
            acc[1][mt] = MFMA(hsa, W4, MFMA(xa, W1, acc[1][mt]));
            acc[2][mt] = MFMA(hsa, W5, MFMA(xa, W2, acc[2][mt]));
            acc[3][mt] = MFMA(xa,  W6, acc[3][mt]);
            acc[4][mt] = MFMA(h0a, W7, acc[4][mt]);
            acc[5][mt] = MFMA(h1a, W7, acc[5][mt]);
        }
    }

    float bi  = b_iou[      feat] + b_Uiou[      feat];
    float bo  = b_iou[128 + feat] + b_Uiou[128 + feat];
    float bu  = b_iou[256 + feat] + b_Uiou[256 + feat];
    float bfv = b_Wf[feat] + b_Uf[feat];
#pragma unroll
    for (int mt = 0; mt < 2; ++mt) {
        float hpair = 0.f;
#pragma unroll
        for (int r = 0; r < 4; ++r) {
            int nb = mt * 16 + kg * 4 + r;
            int g  = n0 + nb;
            float iv = sig_(acc[0][mt][r] + bi);
            float ov = sig_(acc[1][mt][r] + bo);
            float uv = th_ (acc[2][mt][r] + bu);
            float fx = acc[3][mt][r];
            float f0 = sig_(fx + acc[4][mt][r] + bfv);
            float f1 = sig_(fx + acc[5][mt][r] + bfv);
            float cl = iv * uv + f0 * c0p[mt][r] + f1 * c1p[mt][r];
            float hl = ov * th_(cl);
            h_cur[(size_t)g * H + feat] = f2b(hl);
            c_cur[(size_t)g * H + feat] = f2b(cl);
            if (r & 1) { if (write_hs) hs_cur[(size_t)(g >> 1) * H + feat] = f2b(hpair + hl); }
            else       hpair = hl;
        }
    }

    // logits for the CHILDREN (level+1) from staged h0_s/h1_s (valid since barrier)
    if (tid < 320) {
        int j = tid / 5, c = tid - j * 5;   // child j in [0,64), class c
        const bf16_t* hrow = (j & 1) ? &h1_s[j >> 1][0] : &h0_s[j >> 1][0];
        const float* wo = W_out + c * H;
        float s = 0.f;
#pragma unroll 4
        for (int f = 0; f < H; f += 8) {
            uint4 raw = *(const uint4*)&hrow[f];
            s += b2f(raw.x & 0xffff) * wo[f]     + b2f(raw.x >> 16) * wo[f + 1]
               + b2f(raw.y & 0xffff) * wo[f + 2] + b2f(raw.y >> 16) * wo[f + 3]
               + b2f(raw.z & 0xffff) * wo[f + 4] + b2f(raw.z >> 16) * wo[f + 5]
               + b2f(raw.w & 0xffff) * wo[f + 6] + b2f(raw.w >> 16) * wo[f + 7];
        }
        int gc = 2 * n0 + j;
        int lc = level + 1;
        int t = gc >> lc, i = gc & ((1 << lc) - 1);
        out[(size_t)((t0 + t) * NPT + (1 << lc) - 1 + i) * 5 + c] = s + b_out[c];
    }
}

// ---------------------------------------------------------------------------
// Root logits (level 0 only): one wave per node
// ---------------------------------------------------------------------------
__global__ void logits_kernel(
    const bf16_t* __restrict__ h_cur, const float* __restrict__ W_out,
    const float* __restrict__ b_out, float* __restrict__ out,
    int level, int M, int t0)
{
    int wv     = (blockIdx.x * blockDim.x + threadIdx.x) >> 6;
    int lane   = threadIdx.x & 63;
    int nwaves = (gridDim.x * blockDim.x) >> 6;
    for (int g = wv; g < M; g += nwaves) {
        int t = g >> level;
        int i = g - (t << level);
        int id = (t0 + t) * NPT + ((1 << level) - 1) + i;
        float h0 = b2f(h_cur[(size_t)g * H + lane]);
        float h1 = b2f(h_cur[(size_t)g * H + 64 + lane]);
#pragma unroll
        for (int c = 0; c < 5; ++c) {
            float p = h0 * W_out[c * H + lane] + h1 * W_out[c * H + 64 + lane];
#pragma unroll
            for (int off = 32; off >= 1; off >>= 1) p += __shfl_xor(p, off, 64);
            if (lane == 0) out[(size_t)id * 5 + c] = p + b_out[c];
        }
    }
}

// ---------------------------------------------------------------------------
extern "C" void kernel_launch(void* const* d_in, const int* in_sizes, int n_in,
                              void* d_out, int out_size, void* d_ws, size_t ws_size,
                              hipStream_t stream)
{
    (void)in_sizes; (void)n_in; (void)out_size;
    const int*   wordid = (const int*)  d_in[0];
    const float* E      = (const float*)d_in[1];
    const float* W_iou  = (const float*)d_in[2];
    const float* b_iou  = (const float*)d_in[3];
    const float* U_iou  = (const float*)d_in[4];
    const float* b_Uiou = (const float*)d_in[5];
    const float* W_f    = (const float*)d_in[6];
    const float* b_Wf   = (const float*)d_in[7];
    const float* U_f    = (const float*)d_in[8];
    const float* b_Uf   = (const float*)d_in[9];
    const float* W_out  = (const float*)d_in[10];
    const float* b_out  = (const float*)d_in[11];
    float* out = (float*)d_out;

    // ws layout: Wb (256 KB) | Eb (8 MB) | per-chunk bf16 ping-pong h/c/hs
    bf16_t* Wb = (bf16_t*)d_ws;
    bf16_t* Eb = Wb + 1024 * H;
    bf16_t* dyn = Eb + (size_t)32000 * H;
    const size_t fixed_bytes = (1024 + 32000) * (size_t)H * 2;

    int C = 1;
    while (C < 16 && fixed_bytes + (size_t)(NTREES / C) * 491520u > ws_size) C <<= 1;
    const int T = NTREES / C;

    bf16_t* hA  = dyn;
    bf16_t* cA  = hA  + (size_t)T * 512 * H;
    bf16_t* hsA = cA  + (size_t)T * 512 * H;
    bf16_t* hB  = hsA + (size_t)T * 256 * H;
    bf16_t* cB  = hB  + (size_t)T * 256 * H;
    bf16_t* hsB = cB  + (size_t)T * 256 * H;

    pack_weights<<<512, 256, 0, stream>>>(W_iou, U_iou, W_f, U_f, Wb);
    pack_E<<<16000, 256, 0, stream>>>(E, Eb);

    for (int chunk = 0; chunk < C; ++chunk) {
        int t0 = chunk * T;
        for (int l = TDEPTH - 1; l >= 0; --l) {
            int M = T << l;
            bf16_t* h_cur  = (l & 1) ? hA  : hB;
            bf16_t* c_cur  = (l & 1) ? cA  : cB;
            bf16_t* hs_cur = (l & 1) ? hsA : hsB;
            bf16_t* h_prev = (l & 1) ? hB  : hA;
            bf16_t* c_prev = (l & 1) ? cB  : cA;
            bf16_t* hs_prev= (l & 1) ? hsB : hsA;

            if (l == TDEPTH - 1) {
                leaf_mfma<<<M / 64, 512, 0, stream>>>(
                    wordid, Eb, Wb, b_iou, b_Uiou, h_cur, c_cur, hs_cur, t0);
            } else {
                internal_mfma<<<M / 32, 512, 0, stream>>>(
                    wordid, Eb, Wb, b_iou, b_Uiou, b_Wf, b_Uf,
                    h_prev, c_prev, hs_prev, h_cur, c_cur, hs_cur,
                    W_out, b_out, out, l, t0, l > 0 ? 1 : 0);
            }
        }
        // root logits (level 0)
        bf16_t* h0buf = hB;   // level 0 is even
        int blocksR = (T / 4 < 4096) ? ((T + 3) / 4) : 4096;
        if (blocksR < 1) blocksR = 1;
        logits_kernel<<<blocksR, 256, 0, stream>>>(h0buf, W_out, b_out, out, 0, T, t0);
    }
}

// Round 9
// 487.782 us; speedup vs baseline: 1.5607x; 1.3247x over previous
//
#include <hip/hip_runtime.h>

#define H 128
#define TDEPTH 10
#define NPT 1023
#define NTREES 512
#define PAD 136       // LDS row stride in bf16 (272 B, 16B-aligned)

typedef unsigned short bf16_t;
typedef __attribute__((ext_vector_type(8))) short bf16x8;
typedef __attribute__((ext_vector_type(4))) float f32x4;

__device__ __forceinline__ float rcp_(float x) { return __builtin_amdgcn_rcpf(x); }
__device__ __forceinline__ float sig_(float x) { return rcp_(1.0f + __expf(-x)); }
__device__ __forceinline__ float th_(float x)  { return 1.0f - 2.0f * rcp_(__expf(2.0f * x) + 1.0f); }
__device__ __forceinline__ float b2f(bf16_t u) {
    union { float f; unsigned int u; } v; v.u = ((unsigned int)u) << 16; return v.f;
}
__device__ __forceinline__ bf16_t f2b(float f) {
    union { float f; unsigned int u; } v; v.f = f;
    return (bf16_t)((v.u + 0x7fffu + ((v.u >> 16) & 1u)) >> 16);   // RNE
}
__device__ __forceinline__ bf16x8 ld8(const bf16_t* p) {
    return *reinterpret_cast<const bf16x8*>(p);
}
#define MFMA(a,b,c) __builtin_amdgcn_mfma_f32_16x16x32_bf16(a,b,c,0,0,0)

// ---------------------------------------------------------------------------
// Weight pack. Elements 0..131071: plane-interleaved Wb[(feat*8 + p)*128 + k],
// p: 0 Wi | 1 Wo | 2 Wu | 3 Ui | 4 Uo | 5 Uu | 6 Wf | 7 Uf.
// Elements 131072..133119: W_out padded to 16 rows x 128 (rows 5-15 zero).
// ---------------------------------------------------------------------------
__global__ void pack_weights(const float* __restrict__ W_iou, const float* __restrict__ U_iou,
                             const float* __restrict__ W_f,   const float* __restrict__ U_f,
                             const float* __restrict__ W_out, bf16_t* __restrict__ Wb)
{
    int i = blockIdx.x * 256 + threadIdx.x;   // 0 .. 133119
    if (i < 131072) {
        int k    = i & 127;
        int p    = (i >> 7) & 7;
        int feat = i >> 10;
        float v;
        switch (p) {
            case 0: v = W_iou[(      feat) * H + k]; break;
            case 1: v = W_iou[(128 + feat) * H + k]; break;
            case 2: v = W_iou[(256 + feat) * H + k]; break;
            case 3: v = U_iou[(      feat) * H + k]; break;
            case 4: v = U_iou[(128 + feat) * H + k]; break;
            case 5: v = U_iou[(256 + feat) * H + k]; break;
            case 6: v = W_f  [feat * H + k]; break;
            default: v = U_f [feat * H + k]; break;
        }
        Wb[i] = f2b(v);
    } else {
        int j = i - 131072;             // 0..2047
        int cls = j >> 7, k = j & 127;
        Wb[i] = f2b(cls < 5 ? W_out[cls * H + k] : 0.0f);
    }
}

__global__ void pack_E(const float* __restrict__ E, bf16_t* __restrict__ Eb)
{
    int i = blockIdx.x * 256 + threadIdx.x;
    Eb[i] = f2b(E[i]);
}

// ---------------------------------------------------------------------------
// Leaf (l=9): 64 nodes/block, 512 threads = 8 feat-waves (16 feats each).
// ---------------------------------------------------------------------------
__global__ __launch_bounds__(512, 4) void leaf_mfma(
    const int* __restrict__ wordid, const bf16_t* __restrict__ Eb,
    const bf16_t* __restrict__ Wb,
    const float* __restrict__ b_iou, const float* __restrict__ b_Uiou,
    bf16_t* __restrict__ h_cur, bf16_t* __restrict__ c_cur,
    bf16_t* __restrict__ hs_cur, int t0)
{
    const int level = TDEPTH - 1;
    __shared__ __align__(16) bf16_t x_s[64][PAD];

    const int tid = threadIdx.x;
    const int n0  = blockIdx.x * 64;

    for (int idx = tid; idx < 1024; idx += 512) {
        int q = idx & 15;
        int m = idx >> 4;
        int g = n0 + m;
        int t = g >> level, i = g & ((1 << level) - 1);
        int wid = wordid[(t0 + t) * NPT + (1 << level) - 1 + i];
        *(uint4*)&x_s[m][q * 8] = *(const uint4*)(Eb + (size_t)wid * H + q * 8);
    }
    __syncthreads();

    const int lane = tid & 63;
    const int w    = tid >> 6;
    const int l15  = lane & 15;
    const int kg   = lane >> 4;
    const int feat = w * 16 + l15;
    const bf16_t* wbase = Wb + (size_t)feat * 1024 + kg * 8;

    f32x4 z = {0.f, 0.f, 0.f, 0.f};
    f32x4 acc[3][4];
#pragma unroll
    for (int g = 0; g < 3; ++g)
#pragma unroll
        for (int m = 0; m < 4; ++m) acc[g][m] = z;

#pragma unroll
    for (int ks = 0; ks < 4; ++ks) {
        bf16x8 W0 = ld8(wbase + ks * 32 + 0 * 128);
        bf16x8 W1 = ld8(wbase + ks * 32 + 1 * 128);
        bf16x8 W2 = ld8(wbase + ks * 32 + 2 * 128);
        const int kc = ks * 32 + kg * 8;
#pragma unroll
        for (int mt = 0; mt < 4; ++mt) {
            bf16x8 xa = ld8(&x_s[mt * 16 + l15][kc]);
            acc[0][mt] = MFMA(xa, W0, acc[0][mt]);
            acc[1][mt] = MFMA(xa, W1, acc[1][mt]);
            acc[2][mt] = MFMA(xa, W2, acc[2][mt]);
        }
    }

    float bi = b_iou[      feat] + b_Uiou[      feat];
    float bo = b_iou[128 + feat] + b_Uiou[128 + feat];
    float bu = b_iou[256 + feat] + b_Uiou[256 + feat];
#pragma unroll
    for (int mt = 0; mt < 4; ++mt) {
        float hpair = 0.f;
#pragma unroll
        for (int r = 0; r < 4; ++r) {
            int g = n0 + mt * 16 + kg * 4 + r;
            float iv = sig_(acc[0][mt][r] + bi);
            float ov = sig_(acc[1][mt][r] + bo);
            float uv = th_ (acc[2][mt][r] + bu);
            float cl = iv * uv;
            float hl = ov * th_(cl);
            h_cur[(size_t)g * H + feat] = f2b(hl);
            c_cur[(size_t)g * H + feat] = f2b(cl);
            if (r & 1) hs_cur[(size_t)(g >> 1) * H + feat] = f2b(hpair + hl);
            else       hpair = hl;
        }
    }
}

// ---------------------------------------------------------------------------
// Internal level l: 32 nodes/block, 512 threads, 52 KB LDS (x,h0,h1,hs,c0,c1).
// Child (level l+1) logits computed via MFMA from staged h0_s/h1_s.
// ---------------------------------------------------------------------------
__global__ __launch_bounds__(512, 4) void internal_mfma(
    const int* __restrict__ wordid, const bf16_t* __restrict__ Eb,
    const bf16_t* __restrict__ Wb,
    const float* __restrict__ b_iou, const float* __restrict__ b_Uiou,
    const float* __restrict__ b_Wf,  const float* __restrict__ b_Uf,
    const bf16_t* __restrict__ h_prev, const bf16_t* __restrict__ c_prev,
    const bf16_t* __restrict__ hs_prev,
    bf16_t* __restrict__ h_cur, bf16_t* __restrict__ c_cur,
    bf16_t* __restrict__ hs_cur,
    const float* __restrict__ b_out, float* __restrict__ out,
    int level, int t0, int write_hs)
{
    __shared__ __align__(16) bf16_t x_s [32][PAD];
    __shared__ __align__(16) bf16_t h0_s[32][PAD];
    __shared__ __align__(16) bf16_t h1_s[32][PAD];
    __shared__ __align__(16) bf16_t hs_s[32][PAD];
    __shared__ __align__(16) bf16_t c0_s[32][PAD];
    __shared__ __align__(16) bf16_t c1_s[32][PAD];

    const int tid = threadIdx.x;
    const int n0  = blockIdx.x * 32;

    // stage 192 rows x 16 uint4 = 3072 uint4 (6 per thread), coalesced
    for (int idx = tid; idx < 3072; idx += 512) {
        int q = idx & 15, rr = idx >> 4;
        const bf16_t* src; bf16_t* dst;
        if (rr < 32) {
            int g = n0 + rr;
            int t = g >> level, i = g & ((1 << level) - 1);
            int wid = wordid[(t0 + t) * NPT + (1 << level) - 1 + i];
            src = Eb + (size_t)wid * H; dst = &x_s[rr][0];
        } else if (rr < 96) {
            int j = rr - 32;
            src = h_prev + (size_t)(2 * n0 + j) * H;
            dst = (j & 1) ? &h1_s[j >> 1][0] : &h0_s[j >> 1][0];
        } else if (rr < 128) {
            int j = rr - 96;
            src = hs_prev + (size_t)(n0 + j) * H; dst = &hs_s[j][0];
        } else {
            int j = rr - 128;
            src = c_prev + (size_t)(2 * n0 + j) * H;
            dst = (j & 1) ? &c1_s[j >> 1][0] : &c0_s[j >> 1][0];
        }
        *(uint4*)(dst + q * 8) = *(const uint4*)(src + q * 8);
    }
    __syncthreads();

    const int lane = tid & 63;
    const int w    = tid >> 6;
    const int l15  = lane & 15;
    const int kg   = lane >> 4;
    const int feat = w * 16 + l15;
    const bf16_t* wbase = Wb + (size_t)feat * 1024 + kg * 8;

    f32x4 z = {0.f, 0.f, 0.f, 0.f};
    f32x4 acc[6][2];
#pragma unroll
    for (int g = 0; g < 6; ++g)
#pragma unroll
        for (int m = 0; m < 2; ++m) acc[g][m] = z;

#pragma unroll
    for (int ks = 0; ks < 4; ++ks) {
        bf16x8 W0 = ld8(wbase + ks * 32 + 0 * 128);
        bf16x8 W1 = ld8(wbase + ks * 32 + 1 * 128);
        bf16x8 W2 = ld8(wbase + ks * 32 + 2 * 128);
        bf16x8 W3 = ld8(wbase + ks * 32 + 3 * 128);
        bf16x8 W4 = ld8(wbase + ks * 32 + 4 * 128);
        bf16x8 W5 = ld8(wbase + ks * 32 + 5 * 128);
        bf16x8 W6 = ld8(wbase + ks * 32 + 6 * 128);
        bf16x8 W7 = ld8(wbase + ks * 32 + 7 * 128);
        const int kc = ks * 32 + kg * 8;
#pragma unroll
        for (int mt = 0; mt < 2; ++mt) {
            const int row = mt * 16 + l15;
            bf16x8 xa  = ld8(&x_s [row][kc]);
            bf16x8 hsa = ld8(&hs_s[row][kc]);
            bf16x8 h0a = ld8(&h0_s[row][kc]);
            bf16x8 h1a = ld8(&h1_s[row][kc]);
            acc[0][mt] = MFMA(hsa, W3, MFMA(xa, W0, acc[0][mt]));
            acc[1][mt] = MFMA(hsa, W4, MFMA(xa, W1, acc[1][mt]));
            acc[2][mt] = MFMA(hsa, W5, MFMA(xa, W2, acc[2][mt]));
            acc[3][mt] = MFMA(xa,  W6, acc[3][mt]);
            acc[4][mt] = MFMA(h0a, W7, acc[4][mt]);
            acc[5][mt] = MFMA(h1a, W7, acc[5][mt]);
        }
    }

    // child (level+1) logits via MFMA: waves 0-3 each handle 16 children.
    // group: w&1 selects node half, w&2 selects child parity buffer.
    if (w < 4) {
        const bf16_t* hbuf = (w & 2) ? &h1_s[0][0] : &h0_s[0][0];
        const int mbase = (w & 1) * 16;
        const bf16_t* Wob = Wb + 131072;
        f32x4 lacc = z;
#pragma unroll
        for (int ks = 0; ks < 4; ++ks) {
            bf16x8 ha = ld8(hbuf + (size_t)(mbase + l15) * PAD + ks * 32 + kg * 8);
            bf16x8 wo = ld8(Wob + (size_t)l15 * 128 + ks * 32 + kg * 8);
            lacc = MFMA(ha, wo, lacc);
        }
        if (l15 < 5) {
            float bo5 = b_out[l15];
            int lc = level + 1;
#pragma unroll
            for (int r = 0; r < 4; ++r) {
                int m  = mbase + kg * 4 + r;
                int gc = 2 * (n0 + m) + ((w & 2) ? 1 : 0);
                int t = gc >> lc, i = gc & ((1 << lc) - 1);
                out[(size_t)((t0 + t) * NPT + (1 << lc) - 1 + i) * 5 + l15] = lacc[r] + bo5;
            }
        }
    }

    float bi  = b_iou[      feat] + b_Uiou[      feat];
    float bo  = b_iou[128 + feat] + b_Uiou[128 + feat];
    float bu  = b_iou[256 + feat] + b_Uiou[256 + feat];
    float bfv = b_Wf[feat] + b_Uf[feat];
#pragma unroll
    for (int mt = 0; mt < 2; ++mt) {
        float hpair = 0.f;
#pragma unroll
        for (int r = 0; r < 4; ++r) {
            int nb = mt * 16 + kg * 4 + r;
            int g  = n0 + nb;
            float iv = sig_(acc[0][mt][r] + bi);
            float ov = sig_(acc[1][mt][r] + bo);
            float uv = th_ (acc[2][mt][r] + bu);
            float fx = acc[3][mt][r];
            float f0 = sig_(fx + acc[4][mt][r] + bfv);
            float f1 = sig_(fx + acc[5][mt][r] + bfv);
            float c0 = b2f(c0_s[nb][feat]);
            float c1 = b2f(c1_s[nb][feat]);
            float cl = iv * uv + f0 * c0 + f1 * c1;
            float hl = ov * th_(cl);
            h_cur[(size_t)g * H + feat] = f2b(hl);
            c_cur[(size_t)g * H + feat] = f2b(cl);
            if (r & 1) { if (write_hs) hs_cur[(size_t)(g >> 1) * H + feat] = f2b(hpair + hl); }
            else       hpair = hl;
        }
    }
}

// ---------------------------------------------------------------------------
// Root logits (level 0 only): one wave per node
// ---------------------------------------------------------------------------
__global__ void logits_kernel(
    const bf16_t* __restrict__ h_cur, const float* __restrict__ W_out,
    const float* __restrict__ b_out, float* __restrict__ out,
    int level, int M, int t0)
{
    int wv     = (blockIdx.x * blockDim.x + threadIdx.x) >> 6;
    int lane   = threadIdx.x & 63;
    int nwaves = (gridDim.x * blockDim.x) >> 6;
    for (int g = wv; g < M; g += nwaves) {
        int t = g >> level;
        int i = g - (t << level);
        int id = (t0 + t) * NPT + ((1 << level) - 1) + i;
        float h0 = b2f(h_cur[(size_t)g * H + lane]);
        float h1 = b2f(h_cur[(size_t)g * H + 64 + lane]);
#pragma unroll
        for (int c = 0; c < 5; ++c) {
            float p = h0 * W_out[c * H + lane] + h1 * W_out[c * H + 64 + lane];
#pragma unroll
            for (int off = 32; off >= 1; off >>= 1) p += __shfl_xor(p, off, 64);
            if (lane == 0) out[(size_t)id * 5 + c] = p + b_out[c];
        }
    }
}

// ---------------------------------------------------------------------------
extern "C" void kernel_launch(void* const* d_in, const int* in_sizes, int n_in,
                              void* d_out, int out_size, void* d_ws, size_t ws_size,
                              hipStream_t stream)
{
    (void)in_sizes; (void)n_in; (void)out_size;
    const int*   wordid = (const int*)  d_in[0];
    const float* E      = (const float*)d_in[1];
    const float* W_iou  = (const float*)d_in[2];
    const float* b_iou  = (const float*)d_in[3];
    const float* U_iou  = (const float*)d_in[4];
    const float* b_Uiou = (const float*)d_in[5];
    const float* W_f    = (const float*)d_in[6];
    const float* b_Wf   = (const float*)d_in[7];
    const float* U_f    = (const float*)d_in[8];
    const float* b_Uf   = (const float*)d_in[9];
    const float* W_out  = (const float*)d_in[10];
    const float* b_out  = (const float*)d_in[11];
    float* out = (float*)d_out;

    // ws layout: Wb (260 KB incl. W_out block) | Eb (8 MB) | bf16 ping-pong h/c/hs
    bf16_t* Wb = (bf16_t*)d_ws;
    bf16_t* Eb = Wb + 133120;
    bf16_t* dyn = Eb + (size_t)32000 * H;
    const size_t fixed_bytes = (133120 + (size_t)32000 * H) * 2;

    int C = 1;
    while (C < 16 && fixed_bytes + (size_t)(NTREES / C) * 491520u > ws_size) C <<= 1;
    const int T = NTREES / C;

    bf16_t* hA  = dyn;
    bf16_t* cA  = hA  + (size_t)T * 512 * H;
    bf16_t* hsA = cA  + (size_t)T * 512 * H;
    bf16_t* hB  = hsA + (size_t)T * 256 * H;
    bf16_t* cB  = hB  + (size_t)T * 256 * H;
    bf16_t* hsB = cB  + (size_t)T * 256 * H;

    pack_weights<<<520, 256, 0, stream>>>(W_iou, U_iou, W_f, U_f, W_out, Wb);
    pack_E<<<16000, 256, 0, stream>>>(E, Eb);

    for (int chunk = 0; chunk < C; ++chunk) {
        int t0 = chunk * T;
        for (int l = TDEPTH - 1; l >= 0; --l) {
            int M = T << l;
            bf16_t* h_cur  = (l & 1) ? hA  : hB;
            bf16_t* c_cur  = (l & 1) ? cA  : cB;
            bf16_t* hs_cur = (l & 1) ? hsA : hsB;
            bf16_t* h_prev = (l & 1) ? hB  : hA;
            bf16_t* c_prev = (l & 1) ? cB  : cA;
            bf16_t* hs_prev= (l & 1) ? hsB : hsA;

            if (l == TDEPTH - 1) {
                leaf_mfma<<<M / 64, 512, 0, stream>>>(
                    wordid, Eb, Wb, b_iou, b_Uiou, h_cur, c_cur, hs_cur, t0);
            } else {
                internal_mfma<<<M / 32, 512, 0, stream>>>(
                    wordid, Eb, Wb, b_iou, b_Uiou, b_Wf, b_Uf,
                    h_prev, c_prev, hs_prev, h_cur, c_cur, hs_cur,
                    b_out, out, l, t0, l > 0 ? 1 : 0);
            }
        }
        // root logits (level 0)
        bf16_t* h0buf = hB;   // level 0 is even
        int blocksR = (T / 4 < 4096) ? ((T + 3) / 4) : 4096;
        if (blocksR < 1) blocksR = 1;
        logits_kernel<<<blocksR, 256, 0, stream>>>(h0buf, W_out, b_out, out, 0, T, t0);
    }
}